// Round 11
// baseline (2460.771 us; speedup 1.0000x reference)
//
#include <hip/hip_runtime.h>
#include <math.h>

#define TDIM 512
#define CCH  128      // channels
#define HW   32       // height == width
#define OCT  4        // out channels per block
#define ICT  2        // planes staged per phase per wave
#define NPH  16       // phases: 16 * ICT = 32 ics per K-slice
#define SW   36       // LDS row stride: 144B = 9*16B, keeps b128 reads aligned
#define TROWS 12      // 8 px rows + 4 halo rows per wave tile
#define PLANE (TROWS * SW)   // 432 floats per staged plane

// Wave-autonomous split-K: block = 8 waves = 4 K-slices x 2 row-groups.
// Each wave owns a PRIVATE LDS tile (2 planes x 12 rows) and stages/computes
// with ZERO barriers in the K-loop (same-wave ds_write->ds_read ordering is
// handled by the compiler's lgkmcnt). r10 showed 32 waves/CU helps but its
// div/mod staging + halo + barriers added 40% VALU overhead; r8 showed the
// barrier'd 2-block structure stalls at 64% VALUBusy. This removes both.
// Weight addresses go through readfirstlane -> provably wave-uniform -> s_load.
// EPI 0: integrate (conv(spike)*sigmoid gate -> mem_post)
// EPI 1: fire      (conv(mem_post) -> sign gate; threshold/reset; emit spikes)
template<int EPI>
__global__ __launch_bounds__(TDIM, 8) void lif_conv(
    const float* __restrict__ cin,   // conv input [B,C,32,32]
    const float* __restrict__ wgt,   // [C,C,5,5] OIHW
    const float* __restrict__ bias,  // [C]
    const float* __restrict__ aux0,  // EPI0: mem_cur ; EPI1: mem_post
    const float* __restrict__ aux1,  // EPI0: x_t     ; EPI1: unused
    float* __restrict__ out0,        // EPI0: mem_post; EPI1: mem_next
    float* __restrict__ out1,        // EPI1: spikes out[t]
    int first)
{
    const int ocg  = blockIdx.x;         // 0..31
    const int half = blockIdx.y;         // 0..1
    const int b    = blockIdx.z;         // 0..15
    const int oc0  = ocg * OCT;
    const int tid  = threadIdx.x;
    const int w    = tid >> 6;           // wave 0..7
    const int lane = tid & 63;
    const int ks   = w >> 1;             // K-slice 0..3 (32 ics each)
    const int rg   = w & 1;              // row-group 0..1
    const int r0   = half * 16 + rg * 8; // first px row of this wave
    const int rl   = lane >> 3;          // 0..7 px row within wave
    const int cl   = (lane & 7) * 4;     // col base, 4 px/thread

    // wave-uniform K-slice in an SGPR: weight addrs become scalar s_loads
    const int sks = __builtin_amdgcn_readfirstlane(ks);

    __shared__ __align__(16) float s_in[8 * ICT * PLANE];   // 27648 B
    float* tin = s_in + w * (ICT * PLANE);

    float acc[OCT][4];
#pragma unroll
    for (int oc = 0; oc < OCT; ++oc)
#pragma unroll
        for (int j = 0; j < 4; ++j) acc[oc][j] = 0.f;

    if (!(EPI == 0 && first)) {
        const int icbase = ks * 32;      // vector side (cin addrs)
        const int sicb   = sks * 32;     // scalar side (weight addrs)
        // zero own tile once (halo rows/cols stay zero across phases);
        // wave-private -> NO barrier needed
        for (int i = lane; i < ICT * PLANE; i += 64) tin[i] = 0.f;

        for (int ph = 0; ph < NPH; ++ph) {
            // ---- stage ICT planes, 12 rows each, division-free ----
#pragma unroll
            for (int i = 0; i < 3; ++i) {
                int idx  = i * 64 + lane;            // 0..191
                int p    = (idx >= 96) ? 1 : 0;
                int rem  = idx - p * 96;
                int srow = rem >> 3;                 // 0..11
                int sg   = rem & 7;                  // col group
                int gr   = r0 + srow - 2;            // global row
                if ((unsigned)gr < 32u) {
                    float4 v = *(const float4*)&cin[(((size_t)b * CCH + icbase + ph * ICT + p) * HW + gr) * HW + sg * 4];
                    float* dst = &tin[p * PLANE + srow * SW + 2 + sg * 4];
                    *(float2*)dst       = make_float2(v.x, v.y);
                    *(float2*)(dst + 2) = make_float2(v.z, v.w);
                }
            }
            // ---- compute ICT input channels (no barrier: same-wave LDS) ----
#pragma unroll
            for (int ici = 0; ici < ICT; ++ici) {
                float win5[5][8];
#pragma unroll
                for (int kh = 0; kh < 5; ++kh) {
                    const float* src = &tin[ici * PLANE + (rl + kh) * SW + cl];
                    float4 a = *(const float4*)src;
                    float4 c = *(const float4*)(src + 4);
                    win5[kh][0] = a.x; win5[kh][1] = a.y; win5[kh][2] = a.z; win5[kh][3] = a.w;
                    win5[kh][4] = c.x; win5[kh][5] = c.y; win5[kh][6] = c.z; win5[kh][7] = c.w;
                }
                const float* wb = wgt + ((size_t)oc0 * CCH + sicb + ph * ICT + ici) * 25;
#pragma unroll
                for (int oc = 0; oc < OCT; ++oc) {
                    const float* wo = wb + oc * (CCH * 25);
#pragma unroll
                    for (int kh = 0; kh < 5; ++kh) {
#pragma unroll
                        for (int kw = 0; kw < 5; ++kw) {
                            float wv = wo[kh * 5 + kw];   // SGPR-uniform -> s_load
                            acc[oc][0] += win5[kh][kw]     * wv;
                            acc[oc][1] += win5[kh][kw + 1] * wv;
                            acc[oc][2] += win5[kh][kw + 2] * wv;
                            acc[oc][3] += win5[kh][kw + 3] * wv;
                        }
                    }
                }
            }
        }

        // ---- 4-way K-slice reduction (the only barriers in the kernel) ----
        __syncthreads();
        float* red = s_in;                // reuse staging storage
        if (ks > 0) {
            const int slot = ((ks - 1) * 128 + rg * 64 + lane) * 17;
#pragma unroll
            for (int oc = 0; oc < OCT; ++oc)
#pragma unroll
                for (int j = 0; j < 4; ++j)
                    red[slot + oc * 4 + j] = acc[oc][j];
        }
        __syncthreads();
        if (ks == 0) {
#pragma unroll
            for (int q = 0; q < 3; ++q) {
                const int slot = (q * 128 + rg * 64 + lane) * 17;
#pragma unroll
                for (int oc = 0; oc < OCT; ++oc)
#pragma unroll
                    for (int j = 0; j < 4; ++j)
                        acc[oc][j] += red[slot + oc * 4 + j];
            }
        }
    }

    // ---- epilogue: fused LIF pointwise math, ks==0 waves, float4 I/O ----
    if (ks == 0) {
#pragma unroll
        for (int oc = 0; oc < OCT; ++oc) {
            const size_t pidx = (((size_t)b * CCH + oc0 + oc) * HW + (r0 + rl)) * HW + cl;
            const float bia = bias[oc0 + oc];
            float y[4];
#pragma unroll
            for (int j = 0; j < 4; ++j) y[j] = acc[oc][j] + bia;
            if (EPI == 0) {
                float4 xv = *(const float4*)(aux1 + pidx);
                float4 mv;
                if (first) { mv.x = mv.y = mv.z = mv.w = 0.f; }
                else       mv = *(const float4*)(aux0 + pidx);
                float4 mp;
                mp.x = 0.2f * mv.x + (1.f / (1.f + expf(-y[0]))) * xv.x;
                mp.y = 0.2f * mv.y + (1.f / (1.f + expf(-y[1]))) * xv.y;
                mp.z = 0.2f * mv.z + (1.f / (1.f + expf(-y[2]))) * xv.z;
                mp.w = 0.2f * mv.w + (1.f / (1.f + expf(-y[3]))) * xv.w;
                *(float4*)(out0 + pidx) = mp;
            } else {
                float4 m4 = *(const float4*)(aux0 + pidx);
                float g[4] = {
                    (y[0] > 0.f) ? 1.f : ((y[0] < 0.f) ? -1.f : 0.f),
                    (y[1] > 0.f) ? 1.f : ((y[1] < 0.f) ? -1.f : 0.f),
                    (y[2] > 0.f) ? 1.f : ((y[2] < 0.f) ? -1.f : 0.f),
                    (y[3] > 0.f) ? 1.f : ((y[3] < 0.f) ? -1.f : 0.f)};
                float m[4] = {m4.x, m4.y, m4.z, m4.w};
                float4 mn, sp;
                float s0 = (m[0] > 0.5f) ? 1.f : 0.f;
                float s1 = (m[1] > 0.5f) ? 1.f : 0.f;
                float s2 = (m[2] > 0.5f) ? 1.f : 0.f;
                float s3 = (m[3] > 0.5f) ? 1.f : 0.f;
                mn.x = m[0] * (1.f - s0); sp.x = g[0] * s0;
                mn.y = m[1] * (1.f - s1); sp.y = g[1] * s1;
                mn.z = m[2] * (1.f - s2); sp.z = g[2] * s2;
                mn.w = m[3] * (1.f - s3); sp.w = g[3] * s3;
                *(float4*)(out0 + pidx) = mn;
                *(float4*)(out1 + pidx) = sp;
            }
        }
    }
}

extern "C" void kernel_launch(void* const* d_in, const int* in_sizes, int n_in,
                              void* d_out, int out_size, void* d_ws, size_t ws_size,
                              hipStream_t stream) {
    const float* x      = (const float*)d_in[0];  // [8,16,128,32,32]
    const float* back_w = (const float*)d_in[1];  // [128,128,5,5]
    const float* back_b = (const float*)d_in[2];  // [128]
    const float* ei_w   = (const float*)d_in[3];
    const float* ei_b   = (const float*)d_in[4];
    float* out = (float*)d_out;                   // [8,16,128,32,32] spikes

    const size_t N = (size_t)16 * CCH * HW * HW;  // per-timestep state elements
    float* mem_cur  = (float*)d_ws;               // ping-pong membrane (reset)
    float* mem_post = mem_cur + N;                // post-integrate membrane

    dim3 grid(CCH / OCT, 2, 16);                  // (32, 2, 16) = 1024 blocks

    for (int t = 0; t < 8; ++t) {
        const float* spike_prev = (t == 0) ? x : (out + (size_t)(t - 1) * N);
        // integrate: mem_post = 0.2*mem + sigmoid(conv(spike_prev, back_w)+b) * x[t]
        lif_conv<0><<<grid, TDIM, 0, stream>>>(
            spike_prev, back_w, back_b,
            mem_cur, x + (size_t)t * N,
            mem_post, nullptr, (t == 0) ? 1 : 0);
        // fire: ei = sign(conv(mem_post, ei_w)+b); s = mem_post>0.5;
        //       mem_cur = mem_post*(1-s); out[t] = ei*s
        lif_conv<1><<<grid, TDIM, 0, stream>>>(
            mem_post, ei_w, ei_b,
            mem_post, nullptr,
            mem_cur, out + (size_t)t * N, 0);
    }
}

// Round 12
// 2335.598 us; speedup vs baseline: 1.0536x; 1.0536x over previous
//
#include <hip/hip_runtime.h>
#include <math.h>

#define TDIM 512
#define CCH  128      // channels
#define HW   32       // height == width
#define OCT  4        // out channels per block
#define ICT  2        // planes staged per phase per wave
#define NPH  16       // phases: 16 * ICT = 32 ics per K-slice
#define SW   36       // LDS row stride: 144B = 9*16B, b128-aligned window reads
#define TROWS 20      // 16 px rows + 4 halo rows per wave tile
#define PLANE (TROWS * SW)   // 720 floats per staged plane

// Wave-autonomous split-K, 8 px/thread:
// block = 8 waves = 4 K-slices x 2 row-groups; wave owns 16 rows x 32 cols
// (lane: rl=lane>>2 row, cl=(lane&3)*8 col base) and 32 input channels,
// staged 2 planes at a time into a PRIVATE LDS tile -> ZERO barriers in the
// K-loop. Per (ic,kh): 3 ds_read_b128 (12-float window) feed 160 FMAs
// (4oc x 5kw x 8px) -- half the DS and weight-load cost per FMA of r8.
// Per-thread FMA work = r8 level (r11's regression = halved amortization).
// Weight addrs via readfirstlane'd K-slice -> provably uniform -> s_load.
// EPI 0: integrate (conv(spike)*sigmoid gate -> mem_post)
// EPI 1: fire      (conv(mem_post) -> sign gate; threshold/reset; emit spikes)
template<int EPI>
__global__ __launch_bounds__(TDIM, 2) void lif_conv(
    const float* __restrict__ cin,   // conv input [B,C,32,32]
    const float* __restrict__ wgt,   // [C,C,5,5] OIHW
    const float* __restrict__ bias,  // [C]
    const float* __restrict__ aux0,  // EPI0: mem_cur ; EPI1: mem_post
    const float* __restrict__ aux1,  // EPI0: x_t     ; EPI1: unused
    float* __restrict__ out0,        // EPI0: mem_post; EPI1: mem_next
    float* __restrict__ out1,        // EPI1: spikes out[t]
    int first)
{
    const int ocg  = blockIdx.x;         // 0..31
    const int b    = blockIdx.y;         // 0..15
    const int oc0  = ocg * OCT;
    const int tid  = threadIdx.x;
    const int w    = tid >> 6;           // wave 0..7
    const int lane = tid & 63;
    const int ks   = w >> 1;             // K-slice 0..3 (32 ics each)
    const int rg   = w & 1;              // row-group 0..1 (16 rows each)
    const int r0   = rg * 16;            // first px row of this wave
    const int rl   = lane >> 2;          // 0..15 px row within wave
    const int cl   = (lane & 3) * 8;     // col base, 8 px/thread

    // wave-uniform K-slice in an SGPR: weight addrs become scalar s_loads
    const int sks = __builtin_amdgcn_readfirstlane(ks);

    __shared__ __align__(16) float s_in[8 * ICT * PLANE];   // 46080 B
    float* tin = s_in + w * (ICT * PLANE);

    float acc[OCT][8];
#pragma unroll
    for (int oc = 0; oc < OCT; ++oc)
#pragma unroll
        for (int j = 0; j < 8; ++j) acc[oc][j] = 0.f;

    if (!(EPI == 0 && first)) {
        const int icbase = ks * 32;      // vector side (cin addrs)
        const int sicb   = sks * 32;     // scalar side (weight addrs)
        // zero own tile once (halo rows/cols stay zero); wave-private: no barrier
        for (int i = lane; i < ICT * PLANE; i += 64) tin[i] = 0.f;

        for (int ph = 0; ph < NPH; ++ph) {
            // ---- stage ICT planes x 20 rows x 32 cols, division-free ----
#pragma unroll
            for (int i = 0; i < 5; ++i) {
                int idx  = i * 64 + lane;            // 0..319
                int p    = (idx >= 160) ? 1 : 0;     // plane
                int rem  = idx - p * 160;
                int srow = rem >> 3;                 // 0..19
                int sg   = rem & 7;                  // col group
                int gr   = r0 + srow - 2;            // global row
                if ((unsigned)gr < 32u) {
                    float4 v = *(const float4*)&cin[(((size_t)b * CCH + icbase + ph * ICT + p) * HW + gr) * HW + sg * 4];
                    float* dst = &tin[p * PLANE + srow * SW + 2 + sg * 4];
                    *(float2*)dst       = make_float2(v.x, v.y);
                    *(float2*)(dst + 2) = make_float2(v.z, v.w);
                }
            }
            // ---- compute ICT input channels (no barrier: same-wave LDS) ----
#pragma unroll
            for (int ici = 0; ici < ICT; ++ici) {
                const float* wb = wgt + ((size_t)oc0 * CCH + sicb + ph * ICT + ici) * 25;
#pragma unroll
                for (int kh = 0; kh < 5; ++kh) {
                    const float* src = &tin[ici * PLANE + (rl + kh) * SW + cl];
                    float4 a  = *(const float4*)src;
                    float4 c2 = *(const float4*)(src + 4);
                    float4 e  = *(const float4*)(src + 8);
                    float wn[12] = {a.x, a.y, a.z, a.w, c2.x, c2.y, c2.z, c2.w,
                                    e.x, e.y, e.z, e.w};
#pragma unroll
                    for (int oc = 0; oc < OCT; ++oc) {
                        const float* wo = wb + oc * (CCH * 25) + kh * 5;
#pragma unroll
                        for (int kw = 0; kw < 5; ++kw) {
                            float wv = wo[kw];        // SGPR-uniform -> s_load
#pragma unroll
                            for (int px = 0; px < 8; ++px)
                                acc[oc][px] += wn[px + kw] * wv;
                        }
                    }
                }
            }
        }

        // ---- 4-way K-slice reduction, two rounds (only barriers in kernel) ----
        __syncthreads();
        float* red = s_in;                // reuse staging storage (stride 34)
        if (ks == 1 || ks == 2) {
            const int slot = ((ks - 1) * 128 + rg * 64 + lane) * 34;
#pragma unroll
            for (int oc = 0; oc < OCT; ++oc)
#pragma unroll
                for (int j = 0; j < 8; ++j)
                    red[slot + oc * 8 + j] = acc[oc][j];
        }
        __syncthreads();
        if (ks == 0) {
            const int s1 = (rg * 64 + lane) * 34;
            const int s2 = (128 + rg * 64 + lane) * 34;
#pragma unroll
            for (int oc = 0; oc < OCT; ++oc)
#pragma unroll
                for (int j = 0; j < 8; ++j)
                    acc[oc][j] += red[s1 + oc * 8 + j] + red[s2 + oc * 8 + j];
        }
        __syncthreads();
        if (ks == 3) {
            const int slot = (rg * 64 + lane) * 34;
#pragma unroll
            for (int oc = 0; oc < OCT; ++oc)
#pragma unroll
                for (int j = 0; j < 8; ++j)
                    red[slot + oc * 8 + j] = acc[oc][j];
        }
        __syncthreads();
        if (ks == 0) {
            const int slot = (rg * 64 + lane) * 34;
#pragma unroll
            for (int oc = 0; oc < OCT; ++oc)
#pragma unroll
                for (int j = 0; j < 8; ++j)
                    acc[oc][j] += red[slot + oc * 8 + j];
        }
    }

    // ---- epilogue: fused LIF pointwise math, ks==0 waves, 2x float4 I/O ----
    if (ks == 0) {
#pragma unroll
        for (int oc = 0; oc < OCT; ++oc) {
            const size_t pidx = (((size_t)b * CCH + oc0 + oc) * HW + (r0 + rl)) * HW + cl;
            const float bia = bias[oc0 + oc];
            float y[8];
#pragma unroll
            for (int j = 0; j < 8; ++j) y[j] = acc[oc][j] + bia;
            if (EPI == 0) {
                float4 xv0 = *(const float4*)(aux1 + pidx);
                float4 xv1 = *(const float4*)(aux1 + pidx + 4);
                float xv[8] = {xv0.x, xv0.y, xv0.z, xv0.w, xv1.x, xv1.y, xv1.z, xv1.w};
                float mv[8] = {0.f, 0.f, 0.f, 0.f, 0.f, 0.f, 0.f, 0.f};
                if (!first) {
                    float4 m0 = *(const float4*)(aux0 + pidx);
                    float4 m1 = *(const float4*)(aux0 + pidx + 4);
                    mv[0] = m0.x; mv[1] = m0.y; mv[2] = m0.z; mv[3] = m0.w;
                    mv[4] = m1.x; mv[5] = m1.y; mv[6] = m1.z; mv[7] = m1.w;
                }
                float mp[8];
#pragma unroll
                for (int j = 0; j < 8; ++j)
                    mp[j] = 0.2f * mv[j] + (1.f / (1.f + expf(-y[j]))) * xv[j];
                *(float4*)(out0 + pidx)     = make_float4(mp[0], mp[1], mp[2], mp[3]);
                *(float4*)(out0 + pidx + 4) = make_float4(mp[4], mp[5], mp[6], mp[7]);
            } else {
                float4 m0 = *(const float4*)(aux0 + pidx);
                float4 m1 = *(const float4*)(aux0 + pidx + 4);
                float m[8] = {m0.x, m0.y, m0.z, m0.w, m1.x, m1.y, m1.z, m1.w};
                float mn[8], sp[8];
#pragma unroll
                for (int j = 0; j < 8; ++j) {
                    float g = (y[j] > 0.f) ? 1.f : ((y[j] < 0.f) ? -1.f : 0.f);
                    float s = (m[j] > 0.5f) ? 1.f : 0.f;
                    mn[j] = m[j] * (1.f - s);
                    sp[j] = g * s;
                }
                *(float4*)(out0 + pidx)     = make_float4(mn[0], mn[1], mn[2], mn[3]);
                *(float4*)(out0 + pidx + 4) = make_float4(mn[4], mn[5], mn[6], mn[7]);
                *(float4*)(out1 + pidx)     = make_float4(sp[0], sp[1], sp[2], sp[3]);
                *(float4*)(out1 + pidx + 4) = make_float4(sp[4], sp[5], sp[6], sp[7]);
            }
        }
    }
}

extern "C" void kernel_launch(void* const* d_in, const int* in_sizes, int n_in,
                              void* d_out, int out_size, void* d_ws, size_t ws_size,
                              hipStream_t stream) {
    const float* x      = (const float*)d_in[0];  // [8,16,128,32,32]
    const float* back_w = (const float*)d_in[1];  // [128,128,5,5]
    const float* back_b = (const float*)d_in[2];  // [128]
    const float* ei_w   = (const float*)d_in[3];
    const float* ei_b   = (const float*)d_in[4];
    float* out = (float*)d_out;                   // [8,16,128,32,32] spikes

    const size_t N = (size_t)16 * CCH * HW * HW;  // per-timestep state elements
    float* mem_cur  = (float*)d_ws;               // ping-pong membrane (reset)
    float* mem_post = mem_cur + N;                // post-integrate membrane

    dim3 grid(CCH / OCT, 16);                     // (32, 16) = 512 blocks

    for (int t = 0; t < 8; ++t) {
        const float* spike_prev = (t == 0) ? x : (out + (size_t)(t - 1) * N);
        // integrate: mem_post = 0.2*mem + sigmoid(conv(spike_prev, back_w)+b) * x[t]
        lif_conv<0><<<grid, TDIM, 0, stream>>>(
            spike_prev, back_w, back_b,
            mem_cur, x + (size_t)t * N,
            mem_post, nullptr, (t == 0) ? 1 : 0);
        // fire: ei = sign(conv(mem_post, ei_w)+b); s = mem_post>0.5;
        //       mem_cur = mem_post*(1-s); out[t] = ei*s
        lif_conv<1><<<grid, TDIM, 0, stream>>>(
            mem_post, ei_w, ei_b,
            mem_post, nullptr,
            mem_cur, out + (size_t)t * N, 0);
    }
}

// Round 13
// 2271.658 us; speedup vs baseline: 1.0832x; 1.0281x over previous
//
#include <hip/hip_runtime.h>
#include <math.h>

#define TDIM 512
#define CCH  128      // channels
#define HW   32       // height == width
#define OCT  4        // out channels per block
#define NPH  32       // phases: 2 input channels per phase per team
#define PSW  36       // padded row stride (2+32+2)
#define PPL  1296     // padded plane: 36 rows x 36 cols
#define NCHK 11       // DMA chunks of 256 floats covering 2 planes (2592)
#define LDSPH 2816    // LDS floats per (team,buf) = NCHK*256 (pad absorbs tail)

// Conv inputs live PRE-PADDED in global ws ([B,C,36,36], borders zeroed once):
// EPI0's epilogue writes mem_post padded (pad0), EPI1's writes spikes padded
// (pad1) alongside the normal d_out copy. Staging is then pure DMA:
// 11 global_load_lds_dwordx4 per wave per phase (lane-linear dest, zero
// VGPRs, zero ds_writes), double-buffered with ONE barrier per phase --
// DMA for ph+1 issues right after the barrier and drains free at the next.
// (r5/r9: register prefetch explodes regalloc to the VGPR cap and spills;
// global_load_lds is the only zero-VGPR pipelining path.)
// Compute loop = r8's proven inner loop (2-team split-K, 4px/thread,
// win5[5][8] b128 windows, s_load weights via readfirstlane'd team).
// EPI0 epilogue recomputes reset-mem from old pad0 in place (pointwise own-px
// RMW, race-free); EPI1 only reads pad0 -> no cross-block hazard.

__device__ __forceinline__ void gll16(const float* g, float* l) {
    __builtin_amdgcn_global_load_lds(
        (const __attribute__((address_space(1))) unsigned int*)g,
        (__attribute__((address_space(3))) unsigned int*)l, 16, 0, 0);
}

template<int EPI>
__global__ __launch_bounds__(TDIM, 2) void lif_conv(
    const float* __restrict__ cpad,  // padded conv input [B,C,1296]
    const float* __restrict__ wgt,   // [C,C,5,5] OIHW
    const float* __restrict__ bias,  // [C]
    const float* __restrict__ xin,   // EPI0: x_t (normal layout); EPI1 unused
    float* __restrict__ pad0,        // mem_post padded (EPI0 RMW, EPI1 read)
    float* __restrict__ outn,        // EPI1: spikes, normal layout (d_out)
    float* __restrict__ pad1,        // EPI1: spikes, padded copy
    int first)
{
    const int ocg  = blockIdx.x;         // 0..31
    const int b    = blockIdx.y;         // 0..15
    const int oc0  = ocg * OCT;
    const int tid  = threadIdx.x;
    const int team = tid >> 8;           // 0/1 (split-K halves)
    const int lt   = tid & 255;
    const int rl   = lt >> 3;            // 0..31 output row
    const int cl   = (lt & 7) * 4;       // col base, 4 px/thread
    const int wv   = (tid >> 6) & 3;     // wave within team
    const int lane = tid & 63;

    const int steam = __builtin_amdgcn_readfirstlane(team);

    __shared__ __align__(16) float s_in[2 * 2 * LDSPH];   // 45056 B

    float acc[OCT][4];
#pragma unroll
    for (int oc = 0; oc < OCT; ++oc)
#pragma unroll
        for (int j = 0; j < 4; ++j) acc[oc][j] = 0.f;

    if (!(EPI == 0 && first)) {
        const int icb  = team * 64;      // vector side
        const int sicb = steam * 64;     // scalar side (weights)
        float* lbase = s_in + steam * (2 * LDSPH);

        // prologue: DMA phase 0 -> buf 0
        {
            const float* ps = cpad + ((size_t)b * CCH + icb) * PPL;
            for (int j = wv; j < NCHK; j += 4)
                gll16(ps + j * 256 + lane * 4, lbase + j * 256);
        }

        for (int ph = 0; ph < NPH; ++ph) {
            __syncthreads();             // drains this phase's DMA (issued 1 phase ago)
            if (ph < NPH - 1) {          // issue next phase's DMA, hidden under compute
                const float* ps = cpad + ((size_t)b * CCH + icb + (ph + 1) * 2) * PPL;
                float* ld = lbase + ((ph + 1) & 1) * LDSPH;
                for (int j = wv; j < NCHK; j += 4)
                    gll16(ps + j * 256 + lane * 4, ld + j * 256);
            }
            const float* tin = lbase + (ph & 1) * LDSPH;
#pragma unroll
            for (int ici = 0; ici < 2; ++ici) {
                float win5[5][8];
#pragma unroll
                for (int kh = 0; kh < 5; ++kh) {
                    const float* src = tin + ici * PPL + (rl + kh) * PSW + cl;
                    float4 a  = *(const float4*)src;
                    float4 c2 = *(const float4*)(src + 4);
                    win5[kh][0] = a.x;  win5[kh][1] = a.y;  win5[kh][2] = a.z;  win5[kh][3] = a.w;
                    win5[kh][4] = c2.x; win5[kh][5] = c2.y; win5[kh][6] = c2.z; win5[kh][7] = c2.w;
                }
                const float* wb = wgt + ((size_t)oc0 * CCH + sicb + ph * 2 + ici) * 25;
#pragma unroll
                for (int oc = 0; oc < OCT; ++oc) {
                    const float* wo = wb + oc * (CCH * 25);
#pragma unroll
                    for (int kh = 0; kh < 5; ++kh) {
#pragma unroll
                        for (int kw = 0; kw < 5; ++kw) {
                            float wv2 = wo[kh * 5 + kw];   // SGPR-uniform -> s_load
                            acc[oc][0] += win5[kh][kw]     * wv2;
                            acc[oc][1] += win5[kh][kw + 1] * wv2;
                            acc[oc][2] += win5[kh][kw + 2] * wv2;
                            acc[oc][3] += win5[kh][kw + 3] * wv2;
                        }
                    }
                }
            }
        }

        // ---- split-K reduction: team1 -> LDS (stride 17), team0 adds ----
        __syncthreads();
        float* sred = s_in;
        if (team == 1) {
#pragma unroll
            for (int oc = 0; oc < OCT; ++oc)
#pragma unroll
                for (int j = 0; j < 4; ++j)
                    sred[lt * 17 + oc * 4 + j] = acc[oc][j];
        }
        __syncthreads();
        if (team == 0) {
#pragma unroll
            for (int oc = 0; oc < OCT; ++oc)
#pragma unroll
                for (int j = 0; j < 4; ++j)
                    acc[oc][j] += sred[lt * 17 + oc * 4 + j];
        }
    }

    // ---- epilogue: fused LIF pointwise math, team 0 only ----
    if (team == 0) {
#pragma unroll
        for (int oc = 0; oc < OCT; ++oc) {
            const size_t pidxn = (((size_t)b * CCH + oc0 + oc) * HW + rl) * HW + cl;
            const size_t pidxp = ((size_t)b * CCH + oc0 + oc) * PPL + (rl + 2) * PSW + 2 + cl;
            const float bia = bias[oc0 + oc];
            float y[4];
#pragma unroll
            for (int j = 0; j < 4; ++j) y[j] = acc[oc][j] + bia;
            if (EPI == 0) {
                float4 xv = *(const float4*)(xin + pidxn);
                float xr[4] = {xv.x, xv.y, xv.z, xv.w};
                float mo[4] = {0.f, 0.f, 0.f, 0.f};
                if (!first) {
                    float2 a = *(const float2*)(pad0 + pidxp);
                    float2 c = *(const float2*)(pad0 + pidxp + 2);
                    mo[0] = a.x; mo[1] = a.y; mo[2] = c.x; mo[3] = c.y;
                }
                float mp[4];
#pragma unroll
                for (int j = 0; j < 4; ++j) {
                    // recompute reset-mem from previous mem_post (in-place RMW)
                    float mv = (mo[j] > 0.5f) ? 0.f : mo[j];
                    mp[j] = 0.2f * mv + (1.f / (1.f + expf(-y[j]))) * xr[j];
                }
                *(float2*)(pad0 + pidxp)     = make_float2(mp[0], mp[1]);
                *(float2*)(pad0 + pidxp + 2) = make_float2(mp[2], mp[3]);
            } else {
                float2 a = *(const float2*)(pad0 + pidxp);
                float2 c = *(const float2*)(pad0 + pidxp + 2);
                float m[4] = {a.x, a.y, c.x, c.y};
                float sp[4];
#pragma unroll
                for (int j = 0; j < 4; ++j) {
                    float g = (y[j] > 0.f) ? 1.f : ((y[j] < 0.f) ? -1.f : 0.f);
                    float s = (m[j] > 0.5f) ? 1.f : 0.f;
                    sp[j] = g * s;
                }
                *(float4*)(outn + pidxn) = make_float4(sp[0], sp[1], sp[2], sp[3]);
                *(float2*)(pad1 + pidxp)     = make_float2(sp[0], sp[1]);
                *(float2*)(pad1 + pidxp + 2) = make_float2(sp[2], sp[3]);
            }
        }
    }
}

extern "C" void kernel_launch(void* const* d_in, const int* in_sizes, int n_in,
                              void* d_out, int out_size, void* d_ws, size_t ws_size,
                              hipStream_t stream) {
    const float* x      = (const float*)d_in[0];  // [8,16,128,32,32]
    const float* back_w = (const float*)d_in[1];  // [128,128,5,5]
    const float* back_b = (const float*)d_in[2];  // [128]
    const float* ei_w   = (const float*)d_in[3];
    const float* ei_b   = (const float*)d_in[4];
    float* out = (float*)d_out;                   // [8,16,128,32,32] spikes

    const size_t N     = (size_t)16 * CCH * HW * HW;   // 2,097,152
    const size_t PADSZ = (size_t)16 * CCH * PPL;       // 2,654,208
    float* pad0 = (float*)d_ws;           // mem_post padded
    float* pad1 = pad0 + PADSZ;           // spikes padded

    // zero both padded buffers: borders stay zero forever (interiors are
    // fully rewritten each step); idempotent across graph replays
    hipMemsetAsync(d_ws, 0, 2 * PADSZ * sizeof(float), stream);

    dim3 grid(CCH / OCT, 16);             // (32, 16) = 512 blocks

    for (int t = 0; t < 8; ++t) {
        // integrate: mem_post = 0.2*reset(mem_post_old) + sigmoid(conv(spike,back_w)+b)*x[t]
        lif_conv<0><<<grid, TDIM, 0, stream>>>(
            pad1, back_w, back_b,
            x + (size_t)t * N,
            pad0, nullptr, nullptr, (t == 0) ? 1 : 0);
        // fire: ei = sign(conv(mem_post, ei_w)+b); s = mem_post>0.5; spike = ei*s
        lif_conv<1><<<grid, TDIM, 0, stream>>>(
            pad0, ei_w, ei_b,
            nullptr,
            pad0, out + (size_t)t * N, pad1, 0);
    }
}